// Round 2
// baseline (281.086 us; speedup 1.0000x reference)
//
#include <hip/hip_runtime.h>
#include <hip/hip_bf16.h>
#include <stdint.h>

typedef __bf16 bf16_8 __attribute__((ext_vector_type(8)));
typedef float f32x4 __attribute__((ext_vector_type(4)));
typedef unsigned int u32;
typedef unsigned short u16;

// Problem dims (fixed): B=8, R=4, N=1024, D_IN=D_OUT=256.
// Inputs are FP32 (per reference); internal GEMMs run bf16 MFMA; output FP32.

__device__ __forceinline__ u16 f2b(float f) {
    return __builtin_bit_cast(u16, __float2bfloat16(f));
}

// LDS tile: 128 rows x 32 k (bf16) stored as 16B chunks, 4 chunks/row.
// Chunk (row, g) lives at index row*4 + (g ^ ((row>>1)&3)) -> XOR swizzle keeps
// frag reads (fixed g, 16 consecutive rows) at <=2-way bank conflict (free, m136).
__device__ __forceinline__ u32 swz_off(u32 row, u32 g) {
    return (row * 4u + (g ^ ((row >> 1) & 3u))) * 16u;
}

__device__ __forceinline__ void gload_lds16(const void* g, void* l) {
    __builtin_amdgcn_global_load_lds((const __attribute__((address_space(1))) void*)g,
                                     (__attribute__((address_space(3))) void*)l, 16, 0, 0);
}

// C[128x128] += A[128xK] * B[Kx128]; A row-major (k contig, strideA elems),
// B TRANSPOSED (rows = n dim, k contig, strideB elems). 256 thr = 4 waves, 2x2
// wave grid of 64x64 tiles, 16x16x32 bf16 MFMA.
template <int KSTEPS>
__device__ __forceinline__ void gemm_core(const u16* pA, u32 strideA,
                                          const u16* pB, u32 strideB,
                                          char* smem, f32x4 acc[4][4]) {
    char* smA = smem;
    char* smB = smem + 8192;
    const u32 t    = threadIdx.x;
    const u32 lane = t & 63u;
    const u32 w    = t >> 6;
    const u32 wm   = (w >> 1) * 64u;
    const u32 wn   = (w & 1u) * 64u;
    const u32 waveByte = (t & 192u) * 16u;           // wave-uniform LDS dst base
    // staging: thread t fills LDS chunks t and t+256 (rows 0..63 / 64..127)
    const u32 row0 = t >> 2;
    const u32 gg0  = (t & 3u) ^ ((row0 >> 1) & 3u);
    const u32 row1 = (t + 256u) >> 2;
    const u32 gg1  = ((t + 256u) & 3u) ^ ((row1 >> 1) & 3u);
    const u32 fr = lane & 15u;  // frag m/n within 16x16 tile
    const u32 fg = lane >> 4;   // frag k-group (8 bf16)

    for (int ks = 0; ks < KSTEPS; ++ks) {
        const u32 k0 = (u32)ks * 32u;
        __syncthreads();  // protect LDS vs previous iter's readers
        gload_lds16(pA + (size_t)row0 * strideA + k0 + gg0 * 8u, smA + waveByte);
        gload_lds16(pA + (size_t)row1 * strideA + k0 + gg1 * 8u, smA + waveByte + 4096u);
        gload_lds16(pB + (size_t)row0 * strideB + k0 + gg0 * 8u, smB + waveByte);
        gload_lds16(pB + (size_t)row1 * strideB + k0 + gg1 * 8u, smB + waveByte + 4096u);
        __syncthreads();  // compiler drains vmcnt before s_barrier

        bf16_8 af[4], bfv[4];
#pragma unroll
        for (int mt = 0; mt < 4; ++mt) {
            uint4 v = *(const uint4*)(smA + swz_off(wm + (u32)mt * 16u + fr, fg));
            af[mt] = __builtin_bit_cast(bf16_8, v);
        }
#pragma unroll
        for (int nt = 0; nt < 4; ++nt) {
            uint4 v = *(const uint4*)(smB + swz_off(wn + (u32)nt * 16u + fr, fg));
            bfv[nt] = __builtin_bit_cast(bf16_8, v);
        }
#pragma unroll
        for (int mt = 0; mt < 4; ++mt)
#pragma unroll
            for (int nt = 0; nt < 4; ++nt)
                acc[mt][nt] = __builtin_amdgcn_mfma_f32_16x16x32_bf16(af[mt], bfv[nt],
                                                                      acc[mt][nt], 0, 0, 0);
    }
}

// Fused: adjb = bf16(adj); inv[row] = 1/rowsum_fp32(adj row). One wave per row.
__global__ __launch_bounds__(256) void adj_cvt_kernel(const float* adj, u16* adjb,
                                                      float* inv) {
    const u32 row  = blockIdx.x * 4u + (threadIdx.x >> 6);
    const u32 lane = threadIdx.x & 63u;
    const float4* src = (const float4*)(adj + (size_t)row * 1024u);
    ushort4* dst = (ushort4*)(adjb + (size_t)row * 1024u);
    float s = 0.f;
#pragma unroll
    for (int q = 0; q < 4; ++q) {
        const u32 c4 = lane + (u32)q * 64u;
        float4 v = src[c4];
        s += v.x + v.y + v.z + v.w;
        ushort4 pk;
        pk.x = f2b(v.x); pk.y = f2b(v.y); pk.z = f2b(v.z); pk.w = f2b(v.w);
        dst[c4] = pk;
    }
#pragma unroll
    for (int off = 32; off > 0; off >>= 1) s += __shfl_down(s, off, 64);
    if (lane == 0) inv[row] = (s == 0.f) ? 0.f : 1.f / s;
}

// textb = bf16(text), layout preserved [B,N,D_in]. 8 elems/thread.
__global__ __launch_bounds__(256) void text_cvt_kernel(const float* t, u16* tb) {
    const u32 i8 = blockIdx.x * 256u + threadIdx.x;  // 262144 total
    const float4 a = ((const float4*)t)[i8 * 2u];
    const float4 b = ((const float4*)t)[i8 * 2u + 1u];
    uint4 pk;
    pk.x = (u32)f2b(a.x) | ((u32)f2b(a.y) << 16);
    pk.y = (u32)f2b(a.z) | ((u32)f2b(a.w) << 16);
    pk.z = (u32)f2b(b.x) | ((u32)f2b(b.y) << 16);
    pk.w = (u32)f2b(b.z) | ((u32)f2b(b.w) << 16);
    ((uint4*)tb)[i8] = pk;
}

// Wt[r][dout][din] = bf16(W[r][din][dout])
__global__ __launch_bounds__(256) void wt_cvt_kernel(const float* W, u16* Wt) {
    const u32 idx = blockIdx.x * 256u + threadIdx.x;  // 262144 total
    const u32 r = idx >> 16, rem = idx & 65535u, dout = rem >> 8, din = rem & 255u;
    Wt[idx] = f2b(W[(r << 16) + (din << 8) + dout]);
}

// out[b,i,d] = bias[d]  (adj_gemm atomically adds the r-contributions on top)
__global__ __launch_bounds__(256) void bias_init_kernel(const float* bias, float* out) {
    const u32 i4 = blockIdx.x * 256u + threadIdx.x;  // 524288 total, 4 elems each
    ((float4*)out)[i4] = ((const float4*)bias)[i4 & 63u];
}

// Yt[b,r,dout,j] = bf16( sum_din Wt[r,dout,din] * textb[b,j,din] )
__global__ __launch_bounds__(256) void y_gemm_kernel(const u16* Wt, const u16* textb,
                                                     u16* Yt) {
    __shared__ char smem[16384];
    const u32 bx = blockIdx.x;                 // 512 blocks: b(3)|r(2)|m(1)|n(3)
    const u32 n0 = (bx & 7u) * 128u;           // j tile
    const u32 m0 = ((bx >> 3) & 1u) * 128u;    // dout tile
    const u32 r  = (bx >> 4) & 3u;
    const u32 b  = bx >> 6;
    const u16* pA = Wt + (size_t)r * 65536u + (size_t)m0 * 256u;
    const u16* pB = textb + (size_t)b * 262144u + (size_t)n0 * 256u;
    f32x4 acc[4][4];
#pragma unroll
    for (int i = 0; i < 4; ++i)
#pragma unroll
        for (int j = 0; j < 4; ++j) acc[i][j] = (f32x4){0.f, 0.f, 0.f, 0.f};
    gemm_core<8>(pA, 256u, pB, 256u, smem, acc);

    const u32 lane = threadIdx.x & 63u, w = threadIdx.x >> 6;
    const u32 wm = (w >> 1) * 64u, wn = (w & 1u) * 64u;
    const u32 rit = (lane >> 4) * 4u, cit = lane & 15u;  // C: row=(lane>>4)*4+reg, col=lane&15
    u16* yb = Yt + (size_t)(b * 4u + r) * 262144u;
#pragma unroll
    for (int mt = 0; mt < 4; ++mt)
#pragma unroll
        for (int nt = 0; nt < 4; ++nt) {
            const u32 m = m0 + wm + (u32)mt * 16u + rit;
            const u32 n = n0 + wn + (u32)nt * 16u + cit;
#pragma unroll
            for (int rg = 0; rg < 4; ++rg)
                yb[(size_t)(m + (u32)rg) * 1024u + n] = f2b(acc[mt][nt][rg]);
        }
}

// out[b,i,d] += inv[b,r,i] * sum_j adjb[b,r,i,j] * Yt[b,r,d,j]
__global__ __launch_bounds__(256) void adj_gemm_kernel(const u16* adjb, const u16* Yt,
                                                       const float* inv, float* out) {
    __shared__ char smem[16384];
    const u32 bx = blockIdx.x;                 // 512 blocks: b(3)|r(2)|i(3)|n(1)
    const u32 n0 = (bx & 1u) * 128u;           // dout tile
    const u32 m0 = ((bx >> 1) & 7u) * 128u;    // i tile
    const u32 r  = (bx >> 4) & 3u;
    const u32 b  = bx >> 6;
    const u16* pA = adjb + (size_t)(b * 4u + r) * 1048576u + (size_t)m0 * 1024u;
    const u16* pB = Yt + (size_t)(b * 4u + r) * 262144u + (size_t)n0 * 1024u;
    f32x4 acc[4][4];
#pragma unroll
    for (int i = 0; i < 4; ++i)
#pragma unroll
        for (int j = 0; j < 4; ++j) acc[i][j] = (f32x4){0.f, 0.f, 0.f, 0.f};
    gemm_core<32>(pA, 1024u, pB, 1024u, smem, acc);

    const u32 lane = threadIdx.x & 63u, w = threadIdx.x >> 6;
    const u32 wm = (w >> 1) * 64u, wn = (w & 1u) * 64u;
    const u32 rit = (lane >> 4) * 4u, cit = lane & 15u;
    const float* invp = inv + (size_t)(b * 4u + r) * 1024u + m0;
    float* ob = out + (size_t)b * 262144u;
#pragma unroll
    for (int mt = 0; mt < 4; ++mt) {
        const u32 mBase = wm + (u32)mt * 16u + rit;  // i within 128 tile
        float sv[4];
#pragma unroll
        for (int rg = 0; rg < 4; ++rg) sv[rg] = invp[mBase + (u32)rg];
#pragma unroll
        for (int nt = 0; nt < 4; ++nt) {
            const u32 n = n0 + wn + (u32)nt * 16u + cit;
#pragma unroll
            for (int rg = 0; rg < 4; ++rg)
                unsafeAtomicAdd(&ob[(size_t)(m0 + mBase + (u32)rg) * 256u + n],
                                acc[mt][nt][rg] * sv[rg]);
        }
    }
}

extern "C" void kernel_launch(void* const* d_in, const int* in_sizes, int n_in,
                              void* d_out, int out_size, void* d_ws, size_t ws_size,
                              hipStream_t stream) {
    const float* text = (const float*)d_in[0];  // [8,1024,256] fp32
    const float* adj  = (const float*)d_in[1];  // [8,4,1024,1024] fp32
    const float* wgt  = (const float*)d_in[2];  // [4,256,256] fp32
    const float* bias = (const float*)d_in[3];  // [256] fp32
    float* out = (float*)d_out;                 // [8,1024,256] fp32

    char* ws = (char*)d_ws;
    u16* adjb  = (u16*)ws;                          // 64 MB  bf16 [B,R,N,N]
    u16* Yt    = (u16*)(ws + 67108864u);            // 16 MB  bf16 [B,R,256,1024]
    u16* textb = (u16*)(ws + 83886080u);            //  4 MB  bf16 [B,N,256]
    u16* Wt    = (u16*)(ws + 88080384u);            // 512 KB bf16 [R,256,256]
    float* inv = (float*)(ws + 88604672u);          // 128 KB fp32 [B,R,N]

    adj_cvt_kernel<<<8192, 256, 0, stream>>>(adj, adjb, inv);
    text_cvt_kernel<<<1024, 256, 0, stream>>>(text, textb);
    wt_cvt_kernel<<<1024, 256, 0, stream>>>(wgt, Wt);
    bias_init_kernel<<<2048, 256, 0, stream>>>(bias, out);
    y_gemm_kernel<<<512, 256, 0, stream>>>(Wt, textb, Yt);
    adj_gemm_kernel<<<512, 256, 0, stream>>>(adjb, Yt, inv, out);
}

// Round 3
// 250.331 us; speedup vs baseline: 1.1229x; 1.1229x over previous
//
#include <hip/hip_runtime.h>
#include <hip/hip_bf16.h>
#include <stdint.h>

typedef __bf16 bf16_8 __attribute__((ext_vector_type(8)));
typedef float f32x4 __attribute__((ext_vector_type(4)));
typedef unsigned int u32;
typedef unsigned short u16;

// Problem dims (fixed): B=8, R=4, N=1024, D_IN=D_OUT=256.
// Inputs FP32 (per reference); internal GEMMs bf16 MFMA; output FP32.

__device__ __forceinline__ u16 f2b(float f) {
    return __builtin_bit_cast(u16, __float2bfloat16(f));
}

// LDS tile: 128 rows x 32 k (bf16) as 16B chunks, 4 chunks/row.
// Chunk (row,g) at index row*4 + (g ^ ((row>>1)&3)) -> frag reads (fixed g,
// 16 consecutive rows) stay <=2-way bank conflicted (free per m136).
__device__ __forceinline__ u32 swz_off(u32 row, u32 g) {
    return (row * 4u + (g ^ ((row >> 1) & 3u))) * 16u;
}

__device__ __forceinline__ void gload_lds16(const void* g, void* l) {
    __builtin_amdgcn_global_load_lds((const __attribute__((address_space(1))) void*)g,
                                     (__attribute__((address_space(3))) void*)l, 16, 0, 0);
}

__device__ __forceinline__ uint4 pack8(float4 a, float4 b) {
    uint4 pk;
    pk.x = (u32)f2b(a.x) | ((u32)f2b(a.y) << 16);
    pk.y = (u32)f2b(a.z) | ((u32)f2b(a.w) << 16);
    pk.z = (u32)f2b(b.x) | ((u32)f2b(b.y) << 16);
    pk.w = (u32)f2b(b.z) | ((u32)f2b(b.w) << 16);
    return pk;
}

// C[128x128] += A[128xK]*B[Kx128]; A row-major (k contig), B transposed
// (rows = n, k contig). 256 thr = 4 waves, 2x2 grid of 64x64 wave tiles.
template <int KSTEPS>
__device__ __forceinline__ void gemm_core(const u16* pA, u32 strideA,
                                          const u16* pB, u32 strideB,
                                          char* smem, f32x4 acc[4][4]) {
    char* smA = smem;
    char* smB = smem + 8192;
    const u32 t    = threadIdx.x;
    const u32 lane = t & 63u;
    const u32 w    = t >> 6;
    const u32 wm   = (w >> 1) * 64u;
    const u32 wn   = (w & 1u) * 64u;
    const u32 waveByte = (t & 192u) * 16u;           // wave-uniform LDS dst base
    const u32 row0 = t >> 2;
    const u32 gg0  = (t & 3u) ^ ((row0 >> 1) & 3u);
    const u32 row1 = (t + 256u) >> 2;
    const u32 gg1  = ((t + 256u) & 3u) ^ ((row1 >> 1) & 3u);
    const u32 fr = lane & 15u;
    const u32 fg = lane >> 4;

    for (int ks = 0; ks < KSTEPS; ++ks) {
        const u32 k0 = (u32)ks * 32u;
        __syncthreads();
        gload_lds16(pA + (size_t)row0 * strideA + k0 + gg0 * 8u, smA + waveByte);
        gload_lds16(pA + (size_t)row1 * strideA + k0 + gg1 * 8u, smA + waveByte + 4096u);
        gload_lds16(pB + (size_t)row0 * strideB + k0 + gg0 * 8u, smB + waveByte);
        gload_lds16(pB + (size_t)row1 * strideB + k0 + gg1 * 8u, smB + waveByte + 4096u);
        __syncthreads();

        bf16_8 af[4], bfv[4];
#pragma unroll
        for (int mt = 0; mt < 4; ++mt) {
            uint4 v = *(const uint4*)(smA + swz_off(wm + (u32)mt * 16u + fr, fg));
            af[mt] = __builtin_bit_cast(bf16_8, v);
        }
#pragma unroll
        for (int nt = 0; nt < 4; ++nt) {
            uint4 v = *(const uint4*)(smB + swz_off(wn + (u32)nt * 16u + fr, fg));
            bfv[nt] = __builtin_bit_cast(bf16_8, v);
        }
#pragma unroll
        for (int mt = 0; mt < 4; ++mt)
#pragma unroll
            for (int nt = 0; nt < 4; ++nt)
                acc[mt][nt] = __builtin_amdgcn_mfma_f32_16x16x32_bf16(af[mt], bfv[nt],
                                                                      acc[mt][nt], 0, 0, 0);
    }
}

// textb = bf16(text), layout preserved [B,N,D_in]. 8 elems/thread.
__global__ __launch_bounds__(256) void text_cvt_kernel(const float* t, u16* tb) {
    const u32 i8 = blockIdx.x * 256u + threadIdx.x;  // 262144 total
    const float4 a = ((const float4*)t)[i8 * 2u];
    const float4 b = ((const float4*)t)[i8 * 2u + 1u];
    ((uint4*)tb)[i8] = pack8(a, b);
}

// Wt[r][dout][din] = bf16(W[r][din][dout])
__global__ __launch_bounds__(256) void wt_cvt_kernel(const float* W, u16* Wt) {
    const u32 idx = blockIdx.x * 256u + threadIdx.x;  // 262144 total
    const u32 r = idx >> 16, rem = idx & 65535u, dout = rem >> 8, din = rem & 255u;
    Wt[idx] = f2b(W[(r << 16) + (din << 8) + dout]);
}

// Yt[b,r,dout,j] = bf16( sum_din Wt[r,dout,din] * textb[b,j,din] )
__global__ __launch_bounds__(256) void y_gemm_kernel(const u16* Wt, const u16* textb,
                                                     u16* Yt) {
    __shared__ char smem[16384];
    const u32 bx = blockIdx.x;                 // 512 blocks: b(3)|r(2)|m(1)|n(3)
    const u32 n0 = (bx & 7u) * 128u;
    const u32 m0 = ((bx >> 3) & 1u) * 128u;
    const u32 r  = (bx >> 4) & 3u;
    const u32 b  = bx >> 6;
    const u16* pA = Wt + (size_t)r * 65536u + (size_t)m0 * 256u;
    const u16* pB = textb + (size_t)b * 262144u + (size_t)n0 * 256u;
    f32x4 acc[4][4];
#pragma unroll
    for (int i = 0; i < 4; ++i)
#pragma unroll
        for (int j = 0; j < 4; ++j) acc[i][j] = (f32x4){0.f, 0.f, 0.f, 0.f};
    gemm_core<8>(pA, 256u, pB, 256u, smem, acc);

    const u32 lane = threadIdx.x & 63u, w = threadIdx.x >> 6;
    const u32 wm = (w >> 1) * 64u, wn = (w & 1u) * 64u;
    const u32 rit = (lane >> 4) * 4u, cit = lane & 15u;  // C: row=(lane>>4)*4+reg
    u16* yb = Yt + (size_t)(b * 4u + r) * 262144u;
#pragma unroll
    for (int mt = 0; mt < 4; ++mt)
#pragma unroll
        for (int nt = 0; nt < 4; ++nt) {
            const u32 m = m0 + wm + (u32)mt * 16u + rit;
            const u32 n = n0 + wn + (u32)nt * 16u + cit;
#pragma unroll
            for (int rg = 0; rg < 4; ++rg)
                yb[(size_t)(m + (u32)rg) * 1024u + n] = f2b(acc[mt][nt][rg]);
        }
}

// Fused: partial[b,r,i,d] = inv[b,r,i] * sum_j adj[b,r,i,j]*Yt[b,r,d,j]
// where inv = 1/rowsum_fp32(adj row), computed in-block during staging.
// A staged register-mediated (fp32 load -> bf16 cvt -> ds_write); B via
// global_load_lds. A(ks+1) regs prefetched after barrier2 to overlap MFMA.
__global__ __launch_bounds__(256) void adj_gemm_fused(const float* adj, const u16* Yt,
                                                      float* partial) {
    __shared__ char smem[16896];
    char* smA = smem;                     // 8 KB bf16 A-tile (swizzled chunks)
    char* smB = smem + 8192;              // 8 KB bf16 B-tile
    float* sInv = (float*)(smem + 16384); // 128 row inverses

    const u32 bx = blockIdx.x;            // 512 blocks: b(3)|r(2)|i(3)|n(1)
    const u32 n0 = (bx & 1u) * 128u;
    const u32 m0 = ((bx >> 1) & 7u) * 128u;
    const u32 r  = (bx >> 4) & 3u;
    const u32 b  = bx >> 6;

    const float* pA = adj + (size_t)(b * 4u + r) * 1048576u + (size_t)m0 * 1024u;
    const u16*   pB = Yt + (size_t)(b * 4u + r) * 262144u + (size_t)n0 * 1024u;

    const u32 t    = threadIdx.x;
    const u32 lane = t & 63u;
    const u32 w    = t >> 6;
    const u32 wm   = (w >> 1) * 64u;
    const u32 wn   = (w & 1u) * 64u;
    const u32 waveByte = (t & 192u) * 16u;
    const u32 row0 = t >> 2;              // 0..63
    const u32 gg0  = (t & 3u) ^ ((row0 >> 1) & 3u);
    const u32 row1 = row0 + 64u;          // 64..127
    const u32 gg1  = ((t + 256u) & 3u) ^ ((row1 >> 1) & 3u);
    const u32 fr = lane & 15u;
    const u32 fg = lane >> 4;

    f32x4 acc[4][4];
#pragma unroll
    for (int i = 0; i < 4; ++i)
#pragma unroll
        for (int j = 0; j < 4; ++j) acc[i][j] = (f32x4){0.f, 0.f, 0.f, 0.f};

    const float* rp0 = pA + (size_t)row0 * 1024u + gg0 * 8u;
    const float* rp1 = pA + (size_t)row1 * 1024u + gg1 * 8u;
    float4 a0 = *(const float4*)(rp0);
    float4 a1 = *(const float4*)(rp0 + 4);
    float4 a2 = *(const float4*)(rp1);
    float4 a3 = *(const float4*)(rp1 + 4);
    float s0 = 0.f, s1 = 0.f;

    for (int ks = 0; ks < 32; ++ks) {
        const u32 k0 = (u32)ks * 32u;
        __syncthreads();  // LDS consumers of ks-1 done; also drains A-prefetch
        gload_lds16(pB + (size_t)row0 * 1024u + k0 + gg0 * 8u, smB + waveByte);
        gload_lds16(pB + (size_t)row1 * 1024u + k0 + gg1 * 8u, smB + waveByte + 4096u);
        s0 += (a0.x + a0.y + a0.z + a0.w) + (a1.x + a1.y + a1.z + a1.w);
        s1 += (a2.x + a2.y + a2.z + a2.w) + (a3.x + a3.y + a3.z + a3.w);
        *(uint4*)(smA + t * 16u) = pack8(a0, a1);
        *(uint4*)(smA + (t + 256u) * 16u) = pack8(a2, a3);
        __syncthreads();  // drains B gload_lds + A ds_writes

        // prefetch A(ks+1) — latency overlaps frag reads + MFMAs below
        const u32 k1 = (ks < 31) ? (k0 + 32u) : 0u;
        a0 = *(const float4*)(rp0 + k1);
        a1 = *(const float4*)(rp0 + k1 + 4);
        a2 = *(const float4*)(rp1 + k1);
        a3 = *(const float4*)(rp1 + k1 + 4);

        bf16_8 af[4], bfv[4];
#pragma unroll
        for (int mt = 0; mt < 4; ++mt) {
            uint4 v = *(const uint4*)(smA + swz_off(wm + (u32)mt * 16u + fr, fg));
            af[mt] = __builtin_bit_cast(bf16_8, v);
        }
#pragma unroll
        for (int nt = 0; nt < 4; ++nt) {
            uint4 v = *(const uint4*)(smB + swz_off(wn + (u32)nt * 16u + fr, fg));
            bfv[nt] = __builtin_bit_cast(bf16_8, v);
        }
#pragma unroll
        for (int mt = 0; mt < 4; ++mt)
#pragma unroll
            for (int nt = 0; nt < 4; ++nt)
                acc[mt][nt] = __builtin_amdgcn_mfma_f32_16x16x32_bf16(af[mt], bfv[nt],
                                                                      acc[mt][nt], 0, 0, 0);
    }

    // rowsum: 4 consecutive lanes (t&3) hold partials of the same row
    s0 += __shfl_down(s0, 2, 64); s0 += __shfl_down(s0, 1, 64);
    s1 += __shfl_down(s1, 2, 64); s1 += __shfl_down(s1, 1, 64);
    if ((t & 3u) == 0u) {
        sInv[row0] = (s0 == 0.f) ? 0.f : 1.f / s0;
        sInv[row1] = (s1 == 0.f) ? 0.f : 1.f / s1;
    }
    __syncthreads();

    const u32 rit = (lane >> 4) * 4u, cit = lane & 15u;
    float* pp = partial + (size_t)(b * 4u + r) * 262144u;
#pragma unroll
    for (int mt = 0; mt < 4; ++mt) {
        const u32 mBase = wm + (u32)mt * 16u + rit;
        float sv[4];
#pragma unroll
        for (int rg = 0; rg < 4; ++rg) sv[rg] = sInv[mBase + (u32)rg];
#pragma unroll
        for (int nt = 0; nt < 4; ++nt) {
            const u32 n = n0 + wn + (u32)nt * 16u + cit;
#pragma unroll
            for (int rg = 0; rg < 4; ++rg)
                pp[(size_t)(m0 + mBase + (u32)rg) * 256u + n] = acc[mt][nt][rg] * sv[rg];
        }
    }
}

// out[b,i,d] = bias[d] + sum_r partial[b,r,i,d]
__global__ __launch_bounds__(256) void reduce_kernel(const float* partial,
                                                     const float* bias, float* out) {
    const u32 i4 = blockIdx.x * 256u + threadIdx.x;  // 524288 threads, 4 f32 each
    const u32 base = i4 * 4u;
    const u32 b = base >> 18;
    const u32 rem = base & 262143u;
    float4 s = ((const float4*)bias)[i4 & 63u];
#pragma unroll
    for (u32 r = 0; r < 4; ++r) {
        const float4 v = *(const float4*)(partial + (((size_t)(b * 4u + r)) << 18) + rem);
        s.x += v.x; s.y += v.y; s.z += v.z; s.w += v.w;
    }
    ((float4*)out)[i4] = s;
}

extern "C" void kernel_launch(void* const* d_in, const int* in_sizes, int n_in,
                              void* d_out, int out_size, void* d_ws, size_t ws_size,
                              hipStream_t stream) {
    const float* text = (const float*)d_in[0];  // [8,1024,256] fp32
    const float* adj  = (const float*)d_in[1];  // [8,4,1024,1024] fp32
    const float* wgt  = (const float*)d_in[2];  // [4,256,256] fp32
    const float* bias = (const float*)d_in[3];  // [256] fp32
    float* out = (float*)d_out;                 // [8,1024,256] fp32

    char* ws = (char*)d_ws;
    u16* Yt        = (u16*)ws;                      // 16 MB  bf16 [B,R,256,1024]
    u16* textb     = (u16*)(ws + 16777216u);        //  4 MB  bf16 [B,N,256]
    u16* Wt        = (u16*)(ws + 20971520u);        // 512 KB bf16 [R,256,256]
    float* partial = (float*)(ws + 21495808u);      // 32 MB  fp32 [B,R,N,256]

    text_cvt_kernel<<<1024, 256, 0, stream>>>(text, textb);
    wt_cvt_kernel<<<1024, 256, 0, stream>>>(wgt, Wt);
    y_gemm_kernel<<<512, 256, 0, stream>>>(Wt, textb, Yt);
    adj_gemm_fused<<<512, 256, 0, stream>>>(adj, Yt, partial);
    reduce_kernel<<<2048, 256, 0, stream>>>(partial, bias, out);
}